// Round 1
// baseline (1618.148 us; speedup 1.0000x reference)
//
#include <hip/hip_runtime.h>
#include <math.h>

// Problem constants: B=4, N=2048, C=512, H=8, D=64, 3C=1536, scale=1/8.
// d_out layout: out [4,2048,512] (4194304 f32) then attn [4,8,2048,2048].
// ws layout (f32): q[4194304] | k[4194304] | v[4194304]; out_pre aliases q.

#define OFF_K 4194304
#define OFF_V 8388608

// ---------------------------------------------------------------------------
// Kernel 1: qkv = x @ w_qkv, epilogue scatters into q,k,v as [B,H,N,D].
// 128x128 tile, BK=8, 256 threads, 8x8 micro-tile.
// ---------------------------------------------------------------------------
__global__ __launch_bounds__(256) void gemm_qkv_kernel(
    const float* __restrict__ x, const float* __restrict__ w,
    float* __restrict__ qb, float* __restrict__ kb, float* __restrict__ vb)
{
    __shared__ float As[8][132];   // [k][r]
    __shared__ float Bs[8][132];   // [k][c]
    const int tid  = threadIdx.x;
    const int row0 = blockIdx.x * 128;
    const int col0 = blockIdx.y * 128;
    const int tx = tid & 15, ty = tid >> 4;

    float acc[8][8];
    #pragma unroll
    for (int i = 0; i < 8; ++i)
        #pragma unroll
        for (int j = 0; j < 8; ++j) acc[i][j] = 0.0f;

    const int ar  = tid >> 1;          // 0..127
    const int ah  = (tid & 1) * 4;     // 0 or 4
    const int bkr = tid >> 5;          // 0..7
    const int bc  = (tid & 31) * 4;    // 0..124

    for (int k0 = 0; k0 < 512; k0 += 8) {
        float4 a4 = *(const float4*)(x + (size_t)(row0 + ar) * 512 + k0 + ah);
        float4 b4 = *(const float4*)(w + (size_t)(k0 + bkr) * 1536 + col0 + bc);
        __syncthreads();   // previous compute done with As/Bs
        As[ah + 0][ar] = a4.x; As[ah + 1][ar] = a4.y;
        As[ah + 2][ar] = a4.z; As[ah + 3][ar] = a4.w;
        *(float4*)&Bs[bkr][bc] = b4;
        __syncthreads();
        #pragma unroll
        for (int kk = 0; kk < 8; ++kk) {
            float a[8], b[8];
            *(float4*)&a[0] = *(const float4*)&As[kk][ty * 8];
            *(float4*)&a[4] = *(const float4*)&As[kk][ty * 8 + 4];
            *(float4*)&b[0] = *(const float4*)&Bs[kk][tx * 8];
            *(float4*)&b[4] = *(const float4*)&Bs[kk][tx * 8 + 4];
            #pragma unroll
            for (int i = 0; i < 8; ++i)
                #pragma unroll
                for (int j = 0; j < 8; ++j)
                    acc[i][j] = fmaf(a[i], b[j], acc[i][j]);
        }
    }

    // Scatter epilogue: col c -> which=c>>9, h=(c>>6)&7, d=c&63; row r -> b,n.
    #pragma unroll
    for (int i = 0; i < 8; ++i) {
        int r  = row0 + ty * 8 + i;
        int b_ = r >> 11;
        int n  = r & 2047;
        #pragma unroll
        for (int j0 = 0; j0 < 8; j0 += 4) {
            int c     = col0 + tx * 8 + j0;
            int which = c >> 9;
            int h     = (c >> 6) & 7;
            int d     = c & 63;
            float* base = (which == 0) ? qb : ((which == 1) ? kb : vb);
            float* dst  = base + (((size_t)(b_ * 8 + h) * 2048 + n) * 64 + d);
            *(float4*)dst = make_float4(acc[i][j0], acc[i][j0 + 1],
                                        acc[i][j0 + 2], acc[i][j0 + 3]);
        }
    }
}

// ---------------------------------------------------------------------------
// Kernel 2: in-place RoPE on q and k [B,H,N,D]. fp64 angle for accuracy
// (freq*n reaches ~2048 rad; fp32 invf rounding would give ~3e-4 angle error).
// ---------------------------------------------------------------------------
__global__ void rope_kernel(float* __restrict__ qb, float* __restrict__ kb)
{
    int idx = blockIdx.x * 256 + threadIdx.x;   // over B*H*N*32 = 2097152
    if (idx >= 4 * 8 * 2048 * 32) return;
    int i  = idx & 31;
    int n  = (idx >> 5) & 2047;
    int bh = idx >> 16;

    double invf = pow(10000.0, -(double)(2 * i) / 64.0);
    double ang  = (double)n * invf;
    float c = (float)cos(ang);
    float s = (float)sin(ang);

    size_t base = ((size_t)bh * 2048 + n) * 64;
    float q0 = qb[base + i], q1 = qb[base + i + 32];
    qb[base + i]      = q0 * c - q1 * s;
    qb[base + i + 32] = q1 * c + q0 * s;
    float k0 = kb[base + i], k1 = kb[base + i + 32];
    kb[base + i]      = k0 * c - k1 * s;
    kb[base + i + 32] = k1 * c + k0 * s;
}

// ---------------------------------------------------------------------------
// Kernel 3: scores. Per (b*h, 128-row q tile): S = scale * Q K^T written raw
// to attn, running row max / sumexp via LDS reduction, then in-place
// normalize attn rows (re-read is L2-warm).
// ---------------------------------------------------------------------------
__global__ __launch_bounds__(256) void attn_scores_kernel(
    const float* __restrict__ qb, const float* __restrict__ kb,
    float* __restrict__ attn)
{
    __shared__ float Qs[64][132];   // [d][r]
    __shared__ float Ks[64][132];   // [d][c]
    __shared__ float red[128][17];
    __shared__ float m_run[128], l_run[128];

    const int tid = threadIdx.x;
    const int bh  = blockIdx.x;
    const int n0  = blockIdx.y * 128;
    const int tx = tid & 15, ty = tid >> 4;

    const float* qbase = qb + ((size_t)bh * 2048 + n0) * 64;
    const float* kbase = kb + (size_t)bh * 2048 * 64;
    float* attn_base = attn + ((size_t)bh * 2048 + n0) * 2048;

    #pragma unroll
    for (int it = 0; it < 8; ++it) {
        int r = ty + it * 16;
        int d = tx * 4;
        float4 v4 = *(const float4*)(qbase + (size_t)r * 64 + d);
        Qs[d + 0][r] = v4.x; Qs[d + 1][r] = v4.y;
        Qs[d + 2][r] = v4.z; Qs[d + 3][r] = v4.w;
    }
    if (tid < 128) { m_run[tid] = -3.0e38f; l_run[tid] = 0.0f; }
    __syncthreads();

    for (int m0 = 0; m0 < 2048; m0 += 128) {
        // K tile -> regs
        float4 kv[8];
        #pragma unroll
        for (int it = 0; it < 8; ++it) {
            int c = ty + it * 16;
            kv[it] = *(const float4*)(kbase + (size_t)(m0 + c) * 64 + tx * 4);
        }
        __syncthreads();   // prior iter done reading Ks / red
        #pragma unroll
        for (int it = 0; it < 8; ++it) {
            int c = ty + it * 16;
            int d = tx * 4;
            Ks[d + 0][c] = kv[it].x; Ks[d + 1][c] = kv[it].y;
            Ks[d + 2][c] = kv[it].z; Ks[d + 3][c] = kv[it].w;
        }
        __syncthreads();

        float acc[8][8];
        #pragma unroll
        for (int i = 0; i < 8; ++i)
            #pragma unroll
            for (int j = 0; j < 8; ++j) acc[i][j] = 0.0f;

        #pragma unroll 4
        for (int d = 0; d < 64; ++d) {
            float a[8], b[8];
            *(float4*)&a[0] = *(const float4*)&Qs[d][ty * 8];
            *(float4*)&a[4] = *(const float4*)&Qs[d][ty * 8 + 4];
            *(float4*)&b[0] = *(const float4*)&Ks[d][tx * 8];
            *(float4*)&b[4] = *(const float4*)&Ks[d][tx * 8 + 4];
            #pragma unroll
            for (int i = 0; i < 8; ++i)
                #pragma unroll
                for (int j = 0; j < 8; ++j)
                    acc[i][j] = fmaf(a[i], b[j], acc[i][j]);
        }
        #pragma unroll
        for (int i = 0; i < 8; ++i)
            #pragma unroll
            for (int j = 0; j < 8; ++j) acc[i][j] *= 0.125f;

        // write raw scaled scores
        #pragma unroll
        for (int i = 0; i < 8; ++i) {
            int r = ty * 8 + i;
            float* drow = attn_base + (size_t)r * 2048 + m0 + tx * 8;
            *(float4*)drow       = make_float4(acc[i][0], acc[i][1], acc[i][2], acc[i][3]);
            *(float4*)(drow + 4) = make_float4(acc[i][4], acc[i][5], acc[i][6], acc[i][7]);
        }

        // tile row max
        #pragma unroll
        for (int i = 0; i < 8; ++i) {
            float mx = acc[i][0];
            #pragma unroll
            for (int j = 1; j < 8; ++j) mx = fmaxf(mx, acc[i][j]);
            red[ty * 8 + i][tx] = mx;
        }
        __syncthreads();
        if (tid < 128) {
            float tmax = red[tid][0];
            #pragma unroll
            for (int t = 1; t < 16; ++t) tmax = fmaxf(tmax, red[tid][t]);
            float m_old = m_run[tid];
            float m_new = fmaxf(m_old, tmax);
            l_run[tid] *= __expf(m_old - m_new);
            m_run[tid]  = m_new;
        }
        __syncthreads();
        // partial sumexp at the updated max
        #pragma unroll
        for (int i = 0; i < 8; ++i) {
            float mr = m_run[ty * 8 + i];
            float s = 0.0f;
            #pragma unroll
            for (int j = 0; j < 8; ++j) s += __expf(acc[i][j] - mr);
            red[ty * 8 + i][tx] = s;
        }
        __syncthreads();
        if (tid < 128) {
            float s = 0.0f;
            #pragma unroll
            for (int t = 0; t < 16; ++t) s += red[tid][t];
            l_run[tid] += s;
        }
    }
    __syncthreads();
    if (tid < 128) l_run[tid] = 1.0f / l_run[tid];
    __syncthreads();

    // in-place normalize: p = exp(s - m) / l    (rows are contiguous)
    float4* arow = (float4*)attn_base;
    for (int idx = tid; idx < 128 * 512; idx += 256) {
        int r = idx >> 9;
        float m  = m_run[r];
        float li = l_run[r];
        float4 s4 = arow[idx];
        s4.x = __expf(s4.x - m) * li;
        s4.y = __expf(s4.y - m) * li;
        s4.z = __expf(s4.z - m) * li;
        s4.w = __expf(s4.w - m) * li;
        arow[idx] = s4;
    }
}

// ---------------------------------------------------------------------------
// Kernel 4: out_pre[b, n, h*64+d] = attn @ v   per (b*h).
// 128(rows) x 64(D) tile, BK=16 over m, 128 threads, 8x8 micro-tile.
// ---------------------------------------------------------------------------
__global__ __launch_bounds__(128) void attn_pv_kernel(
    const float* __restrict__ attn, const float* __restrict__ vb,
    float* __restrict__ out_pre)
{
    __shared__ float As[16][132];   // [m][r]
    __shared__ float Bs[16][68];    // [m][d]
    const int tid = threadIdx.x;
    const int bh  = blockIdx.x;
    const int n0  = blockIdx.y * 128;
    const int b = bh >> 3, h = bh & 7;
    const int tx = tid & 7, ty = tid >> 3;   // tx: d-group, ty: row-group

    const float* pbase = attn + ((size_t)bh * 2048 + n0) * 2048;
    const float* vbase = vb + (size_t)bh * 2048 * 64;

    float acc[8][8];
    #pragma unroll
    for (int i = 0; i < 8; ++i)
        #pragma unroll
        for (int j = 0; j < 8; ++j) acc[i][j] = 0.0f;

    const int ar  = tid >> 2;         // 0..31
    const int ahh = (tid & 3) * 4;    // m offset
    const int vm  = tid >> 4;         // 0..7
    const int vd  = (tid & 15) * 4;

    for (int m0 = 0; m0 < 2048; m0 += 16) {
        float4 a4[4];
        #pragma unroll
        for (int it = 0; it < 4; ++it) {
            int r = ar + it * 32;
            a4[it] = *(const float4*)(pbase + (size_t)r * 2048 + m0 + ahh);
        }
        float4 b4[2];
        #pragma unroll
        for (int it = 0; it < 2; ++it) {
            int m = vm + it * 8;
            b4[it] = *(const float4*)(vbase + (size_t)(m0 + m) * 64 + vd);
        }
        __syncthreads();
        #pragma unroll
        for (int it = 0; it < 4; ++it) {
            int r = ar + it * 32;
            As[ahh + 0][r] = a4[it].x; As[ahh + 1][r] = a4[it].y;
            As[ahh + 2][r] = a4[it].z; As[ahh + 3][r] = a4[it].w;
        }
        #pragma unroll
        for (int it = 0; it < 2; ++it)
            *(float4*)&Bs[vm + it * 8][vd] = b4[it];
        __syncthreads();
        #pragma unroll 4
        for (int kk = 0; kk < 16; ++kk) {
            float a[8], bb[8];
            *(float4*)&a[0]  = *(const float4*)&As[kk][ty * 8];
            *(float4*)&a[4]  = *(const float4*)&As[kk][ty * 8 + 4];
            *(float4*)&bb[0] = *(const float4*)&Bs[kk][tx * 8];
            *(float4*)&bb[4] = *(const float4*)&Bs[kk][tx * 8 + 4];
            #pragma unroll
            for (int i = 0; i < 8; ++i)
                #pragma unroll
                for (int j = 0; j < 8; ++j)
                    acc[i][j] = fmaf(a[i], bb[j], acc[i][j]);
        }
    }

    #pragma unroll
    for (int i = 0; i < 8; ++i) {
        int n = n0 + ty * 8 + i;
        float* dst = out_pre + ((size_t)b * 2048 + n) * 512 + h * 64 + tx * 8;
        *(float4*)dst       = make_float4(acc[i][0], acc[i][1], acc[i][2], acc[i][3]);
        *(float4*)(dst + 4) = make_float4(acc[i][4], acc[i][5], acc[i][6], acc[i][7]);
    }
}

// ---------------------------------------------------------------------------
// Kernel 5: out = out_pre @ w_proj + b_proj.  Same tiling as kernel 1.
// ---------------------------------------------------------------------------
__global__ __launch_bounds__(256) void proj_kernel(
    const float* __restrict__ a, const float* __restrict__ w,
    const float* __restrict__ bias, float* __restrict__ out)
{
    __shared__ float As[8][132];
    __shared__ float Bs[8][132];
    const int tid  = threadIdx.x;
    const int row0 = blockIdx.x * 128;
    const int col0 = blockIdx.y * 128;
    const int tx = tid & 15, ty = tid >> 4;

    float acc[8][8];
    #pragma unroll
    for (int i = 0; i < 8; ++i)
        #pragma unroll
        for (int j = 0; j < 8; ++j) acc[i][j] = 0.0f;

    const int ar  = tid >> 1;
    const int ah  = (tid & 1) * 4;
    const int bkr = tid >> 5;
    const int bc  = (tid & 31) * 4;

    for (int k0 = 0; k0 < 512; k0 += 8) {
        float4 a4 = *(const float4*)(a + (size_t)(row0 + ar) * 512 + k0 + ah);
        float4 b4 = *(const float4*)(w + (size_t)(k0 + bkr) * 512 + col0 + bc);
        __syncthreads();
        As[ah + 0][ar] = a4.x; As[ah + 1][ar] = a4.y;
        As[ah + 2][ar] = a4.z; As[ah + 3][ar] = a4.w;
        *(float4*)&Bs[bkr][bc] = b4;
        __syncthreads();
        #pragma unroll
        for (int kk = 0; kk < 8; ++kk) {
            float av[8], bv[8];
            *(float4*)&av[0] = *(const float4*)&As[kk][ty * 8];
            *(float4*)&av[4] = *(const float4*)&As[kk][ty * 8 + 4];
            *(float4*)&bv[0] = *(const float4*)&Bs[kk][tx * 8];
            *(float4*)&bv[4] = *(const float4*)&Bs[kk][tx * 8 + 4];
            #pragma unroll
            for (int i = 0; i < 8; ++i)
                #pragma unroll
                for (int j = 0; j < 8; ++j)
                    acc[i][j] = fmaf(av[i], bv[j], acc[i][j]);
        }
    }

    float bj[8];
    #pragma unroll
    for (int j = 0; j < 8; ++j) bj[j] = bias[col0 + tx * 8 + j];

    #pragma unroll
    for (int i = 0; i < 8; ++i) {
        int r = row0 + ty * 8 + i;
        float* dst = out + (size_t)r * 512 + col0 + tx * 8;
        *(float4*)dst       = make_float4(acc[i][0] + bj[0], acc[i][1] + bj[1],
                                          acc[i][2] + bj[2], acc[i][3] + bj[3]);
        *(float4*)(dst + 4) = make_float4(acc[i][4] + bj[4], acc[i][5] + bj[5],
                                          acc[i][6] + bj[6], acc[i][7] + bj[7]);
    }
}

// ---------------------------------------------------------------------------
extern "C" void kernel_launch(void* const* d_in, const int* in_sizes, int n_in,
                              void* d_out, int out_size, void* d_ws, size_t ws_size,
                              hipStream_t stream)
{
    const float* x      = (const float*)d_in[0];
    const float* w_qkv  = (const float*)d_in[1];
    const float* w_proj = (const float*)d_in[2];
    const float* b_proj = (const float*)d_in[3];

    float* out  = (float*)d_out;                 // [4,2048,512]
    float* attn = (float*)d_out + 4194304;       // [4,8,2048,2048]

    float* ws = (float*)d_ws;
    float* q = ws;                // [B,H,N,D]
    float* k = ws + OFF_K;
    float* v = ws + OFF_V;
    float* out_pre = ws;          // aliases q (q dead after attn_scores)

    gemm_qkv_kernel<<<dim3(64, 12), 256, 0, stream>>>(x, w_qkv, q, k, v);
    rope_kernel<<<8192, 256, 0, stream>>>(q, k);
    attn_scores_kernel<<<dim3(32, 16), 256, 0, stream>>>(q, k, attn);
    attn_pv_kernel<<<dim3(32, 16), 128, 0, stream>>>(attn, v, out_pre);
    proj_kernel<<<dim3(64, 4), 256, 0, stream>>>(out_pre, w_proj, b_proj, out);
}